// Round 1
// baseline (176.224 us; speedup 1.0000x reference)
//
#include <hip/hip_runtime.h>
#include <stdint.h>

#define DEVI __device__ __forceinline__

typedef __attribute__((ext_vector_type(8))) short bf16x8;
typedef __attribute__((ext_vector_type(4))) float f32x4;
typedef __attribute__((ext_vector_type(4))) unsigned short u16x4;
typedef __attribute__((ext_vector_type(4))) float float4v;

static constexpr int NB = 8;      // batch
static constexpr int NN = 4096;   // tokens
static constexpr int NC = 512;    // channels
static constexpr int NHD = 8;     // heads
// head dim = 64

DEVI unsigned short f2bf(float f) {
  unsigned int u = __builtin_bit_cast(unsigned int, f);
  u += 0x7FFFu + ((u >> 16) & 1u);
  return (unsigned short)(u >> 16);
}
DEVI float bf2f(short s) {
  unsigned int u = ((unsigned int)(unsigned short)s) << 16;
  return __builtin_bit_cast(float, u);
}
DEVI void gload16(const unsigned short* g, unsigned short* l) {
  __builtin_amdgcn_global_load_lds(
      (const __attribute__((address_space(1))) unsigned int*)g,
      (__attribute__((address_space(3))) unsigned int*)l, 16, 0, 0);
}

// ---------------- K1: f32 -> bf16 cast ----------------
__global__ void cast_kernel(const float4v* __restrict__ src,
                            u16x4* __restrict__ dst, int n4) {
  int stride = gridDim.x * blockDim.x;
  for (int i = blockIdx.x * blockDim.x + threadIdx.x; i < n4; i += stride) {
    float4v f = src[i];
    u16x4 o;
    o.x = f2bf(f.x); o.y = f2bf(f.y); o.z = f2bf(f.z); o.w = f2bf(f.w);
    dst[i] = o;
  }
}

// ---------------- shared GEMM mainloop (128x128 tile, BK=32) ----------------
DEVI void gemm_mainloop(const unsigned short* gA, const unsigned short* gB,
                        unsigned short* lA, unsigned short* lB,
                        unsigned short* lAp, unsigned short* lBp,
                        int wr, int wc, int fr, int kg, f32x4 acc[4][4]) {
  for (int kk = 0; kk < 512; kk += 32) {
    gload16(gA + kk, lAp);
    gload16(gA + kk + 64 * 512, lAp + 2048);
    gload16(gB + kk, lBp);
    gload16(gB + kk + 64 * 512, lBp + 2048);
    __syncthreads();
    bf16x8 af[4], bfv[4];
#pragma unroll
    for (int mi = 0; mi < 4; ++mi)
      af[mi] = *(const bf16x8*)&lA[(wr * 64 + mi * 16 + fr) * 32 + kg * 8];
#pragma unroll
    for (int ni = 0; ni < 4; ++ni)
      bfv[ni] = *(const bf16x8*)&lB[(wc * 64 + ni * 16 + fr) * 32 + kg * 8];
#pragma unroll
    for (int mi = 0; mi < 4; ++mi)
#pragma unroll
      for (int ni = 0; ni < 4; ++ni)
        acc[mi][ni] = __builtin_amdgcn_mfma_f32_16x16x32_bf16(
            af[mi], bfv[ni], acc[mi][ni], 0, 0, 0);
    __syncthreads();
  }
}

// ---------------- K2: qkv GEMM, epilogue splits q/k (transposed) and v ------
__launch_bounds__(256)
__global__ void qkv_gemm(const unsigned short* __restrict__ A,    // Xbf [32768][512]
                         const unsigned short* __restrict__ Bw,   // Wbf [1536][512]
                         unsigned short* __restrict__ vbf,        // [32768][512]
                         unsigned short* __restrict__ qkT) {      // [8192][4096]
  __shared__ __align__(16) unsigned short lA[128 * 32];
  __shared__ __align__(16) unsigned short lB[128 * 32];
  const int tid = threadIdx.x;
  const int wave = tid >> 6, lane = tid & 63;
  const int wr = wave >> 1, wc = wave & 1;
  const int fr = lane & 15, kg = lane >> 4;
  const int rowBase = blockIdx.x * 128;
  const int colBase = blockIdx.y * 128;

  f32x4 acc[4][4] = {};

  const int sRow = wave * 16 + (lane >> 2);
  const int sK = (lane & 3) * 8;
  const unsigned short* gA = A + (size_t)(rowBase + sRow) * 512 + sK;
  const unsigned short* gB = Bw + (size_t)(colBase + sRow) * 512 + sK;
  unsigned short* lAp = lA + wave * 512;
  unsigned short* lBp = lB + wave * 512;

  gemm_mainloop(gA, gB, lA, lB, lAp, lBp, wr, wc, fr, kg, acc);

  const int b = rowBase >> 12;
#pragma unroll
  for (int mi = 0; mi < 4; ++mi) {
    const int rbase = rowBase + wr * 64 + mi * 16 + kg * 4;  // global row of reg 0
#pragma unroll
    for (int ni = 0; ni < 4; ++ni) {
      const int col = colBase + wc * 64 + ni * 16 + fr;
      const int t = col >> 9;
      const int rem = col & 511;
      f32x4 v = acc[mi][ni];
      if (t == 2) {
#pragma unroll
        for (int r = 0; r < 4; ++r)
          vbf[(size_t)(rbase + r) * 512 + rem] = f2bf(v[r]);
      } else {
        const int h = rem >> 6, e = rem & 63;
        const int qrow = ((t * 8 + b) * 8 + h) * 64 + e;
        const int nb = rbase & 4095;
        u16x4 o;
        o.x = f2bf(v[0]); o.y = f2bf(v[1]); o.z = f2bf(v[2]); o.w = f2bf(v[3]);
        *(u16x4*)&qkT[(size_t)qrow * 4096 + nb] = o;
      }
    }
  }
}

// ---------------- K3: per-row sum of squares over n (rows of qkT) ----------
__global__ void sumsq_kernel(const unsigned short* __restrict__ qkT,
                             float* __restrict__ sumsq) {
  const int row = blockIdx.x;  // 0..8191
  const unsigned short* p = qkT + (size_t)row * 4096;
  const int t = threadIdx.x;
  float s = 0.f;
#pragma unroll
  for (int j = 0; j < 2; ++j) {
    bf16x8 v = *(const bf16x8*)(p + t * 8 + j * 2048);
#pragma unroll
    for (int m = 0; m < 8; ++m) {
      float f = bf2f(v[m]);
      s += f * f;
    }
  }
  for (int o = 32; o > 0; o >>= 1) s += __shfl_down(s, o);
  __shared__ float wsum[4];
  if ((t & 63) == 0) wsum[t >> 6] = s;
  __syncthreads();
  if (t == 0) sumsq[row] = wsum[0] + wsum[1] + wsum[2] + wsum[3];
}

// ---------------- K4: gram S = q^T k per (b,h), split-K partials -----------
__launch_bounds__(256)
__global__ void gram_kernel(const unsigned short* __restrict__ qkT,
                            float* __restrict__ Spart) {
  const int bh = blockIdx.x;     // 0..63
  const int chunk = blockIdx.y;  // 0..7
  const int b = bh >> 3, h = bh & 7;
  const unsigned short* qbase = qkT + (size_t)((b * 8 + h) * 64) * 4096;
  const unsigned short* kbase = qkT + (size_t)((64 + b * 8 + h) * 64) * 4096;
  const int wave = threadIdx.x >> 6, lane = threadIdx.x & 63;
  const int wr = wave >> 1, wc = wave & 1;
  const int fr = lane & 15, kg = lane >> 4;
  f32x4 acc[2][2] = {};
  const int k0 = chunk * 512;
  for (int kk = k0; kk < k0 + 512; kk += 32) {
    bf16x8 a[2], bb[2];
#pragma unroll
    for (int mi = 0; mi < 2; ++mi)
      a[mi] = *(const bf16x8*)(qbase + (size_t)(wr * 32 + mi * 16 + fr) * 4096 + kk + kg * 8);
#pragma unroll
    for (int ni = 0; ni < 2; ++ni)
      bb[ni] = *(const bf16x8*)(kbase + (size_t)(wc * 32 + ni * 16 + fr) * 4096 + kk + kg * 8);
#pragma unroll
    for (int mi = 0; mi < 2; ++mi)
#pragma unroll
      for (int ni = 0; ni < 2; ++ni)
        acc[mi][ni] = __builtin_amdgcn_mfma_f32_16x16x32_bf16(a[mi], bb[ni], acc[mi][ni], 0, 0, 0);
  }
  float* Sp = Spart + ((size_t)chunk * 64 + bh) * 4096;
#pragma unroll
  for (int mi = 0; mi < 2; ++mi)
#pragma unroll
    for (int ni = 0; ni < 2; ++ni) {
      f32x4 v = acc[mi][ni];
#pragma unroll
      for (int r = 0; r < 4; ++r)
        Sp[(wr * 32 + mi * 16 + kg * 4 + r) * 64 + wc * 32 + ni * 16 + fr] = v[r];
    }
}

// ---------------- K5a: normalize + softmax over d --------------------------
__global__ void softmax_kernel(const float* __restrict__ Spart,
                               const float* __restrict__ sumsq,
                               const float* __restrict__ temp,
                               float* __restrict__ attnOut) {
  const int bh = blockIdx.x;
  const int b = bh >> 3, h = bh & 7;
  const float* sq = sumsq + (size_t)((b * 8 + h) * 64);
  const float* sk = sumsq + (size_t)((64 + b * 8 + h) * 64);
  const float tmp = temp[h];
  __shared__ float invq[64], invk[64];
  if (threadIdx.x < 64)
    invq[threadIdx.x] = 1.f / fmaxf(sqrtf(sq[threadIdx.x]), 1e-12f);
  else if (threadIdx.x < 128)
    invk[threadIdx.x - 64] = 1.f / fmaxf(sqrtf(sk[threadIdx.x - 64]), 1e-12f);
  __syncthreads();
  const int c = threadIdx.x >> 2, q4 = threadIdx.x & 3;
  float lg[16];
  float mx = -1e30f;
#pragma unroll
  for (int j = 0; j < 16; ++j) {
    const int d = q4 * 16 + j;
    float s = 0.f;
#pragma unroll
    for (int ch = 0; ch < 8; ++ch)
      s += Spart[((size_t)ch * 64 + bh) * 4096 + c * 64 + d];
    lg[j] = s * invq[c] * invk[d] * tmp;
    mx = fmaxf(mx, lg[j]);
  }
  mx = fmaxf(mx, __shfl_xor(mx, 1));
  mx = fmaxf(mx, __shfl_xor(mx, 2));
  float sum = 0.f;
#pragma unroll
  for (int j = 0; j < 16; ++j) {
    lg[j] = __expf(lg[j] - mx);
    sum += lg[j];
  }
  sum += __shfl_xor(sum, 1);
  sum += __shfl_xor(sum, 2);
  const float inv = 1.f / sum;
#pragma unroll
  for (int j = 0; j < 16; ++j)
    attnOut[(size_t)bh * 4096 + c * 64 + q4 * 16 + j] = lg[j] * inv;
}

// ---------------- K5b: Weff[b][:,h-block] = Wproj[:,h-block] @ attn --------
__global__ void weff_kernel(const float* __restrict__ attn,
                            const float* __restrict__ Wproj,
                            unsigned short* __restrict__ Weff) {
  const int bh = blockIdx.x, eb = blockIdx.y;
  const int b = bh >> 3, h = bh & 7;
  __shared__ float at[64 * 64];
  for (int i = threadIdx.x; i < 4096; i += 256)
    at[i] = attn[(size_t)bh * 4096 + i];
  __syncthreads();
  const int e = eb * 64 + (threadIdx.x >> 2);
  const int dq = threadIdx.x & 3;
  float acc[16] = {};
  const float* wrow = Wproj + (size_t)e * 512 + h * 64;
  for (int c = 0; c < 64; ++c) {
    const float w = wrow[c];
#pragma unroll
    for (int j = 0; j < 16; ++j) acc[j] += w * at[c * 64 + dq * 16 + j];
  }
  unsigned short* outp = Weff + ((size_t)b * 512 + e) * 512 + h * 64 + dq * 16;
#pragma unroll
  for (int j = 0; j < 16; ++j) outp[j] = f2bf(acc[j]);
}

// ---------------- K6: final = v @ Weff[b]^T + bproj ------------------------
__launch_bounds__(256)
__global__ void out_gemm(const unsigned short* __restrict__ vbf,
                         const unsigned short* __restrict__ WeffAll,
                         const float* __restrict__ bias,
                         float* __restrict__ out) {
  __shared__ __align__(16) unsigned short lA[128 * 32];
  __shared__ __align__(16) unsigned short lB[128 * 32];
  const int tid = threadIdx.x;
  const int wave = tid >> 6, lane = tid & 63;
  const int wr = wave >> 1, wc = wave & 1;
  const int fr = lane & 15, kg = lane >> 4;
  const int b = blockIdx.z;
  const int rowBase = blockIdx.x * 128;  // within b
  const int colBase = blockIdx.y * 128;
  const unsigned short* A = vbf + (size_t)b * 4096 * 512;
  const unsigned short* Bw = WeffAll + (size_t)b * 512 * 512;

  f32x4 acc[4][4] = {};
  const int sRow = wave * 16 + (lane >> 2);
  const int sK = (lane & 3) * 8;
  const unsigned short* gA = A + (size_t)(rowBase + sRow) * 512 + sK;
  const unsigned short* gB = Bw + (size_t)(colBase + sRow) * 512 + sK;
  unsigned short* lAp = lA + wave * 512;
  unsigned short* lBp = lB + wave * 512;

  gemm_mainloop(gA, gB, lA, lB, lAp, lBp, wr, wc, fr, kg, acc);

#pragma unroll
  for (int mi = 0; mi < 4; ++mi) {
    const int rbase = rowBase + wr * 64 + mi * 16 + kg * 4;
#pragma unroll
    for (int ni = 0; ni < 4; ++ni) {
      const int col = colBase + wc * 64 + ni * 16 + fr;
      const float bcol = bias[col];
      f32x4 v = acc[mi][ni];
#pragma unroll
      for (int r = 0; r < 4; ++r)
        out[((size_t)b * 4096 + rbase + r) * 512 + col] = v[r] + bcol;
    }
  }
}

extern "C" void kernel_launch(void* const* d_in, const int* in_sizes, int n_in,
                              void* d_out, int out_size, void* d_ws, size_t ws_size,
                              hipStream_t stream) {
  const float* x = (const float*)d_in[0];      // [8][4096][512]
  const float* Wqkv = (const float*)d_in[1];   // [1536][512]
  const float* Wproj = (const float*)d_in[2];  // [512][512]
  const float* bproj = (const float*)d_in[3];  // [512]
  const float* temp = (const float*)d_in[4];   // [8]
  float* out = (float*)d_out;

  char* ws = (char*)d_ws;
  unsigned short* Xbf = (unsigned short*)(ws + 0);            // 33,554,432 B
  unsigned short* Wbf = (unsigned short*)(ws + 33554432);     //  1,572,864 B
  unsigned short* vbf = (unsigned short*)(ws + 35127296);     // 33,554,432 B
  unsigned short* qkT = (unsigned short*)(ws + 68681728);     // 67,108,864 B
  float* sumsq = (float*)(ws + 135790592);                    //     32,768 B
  float* Spart = (float*)(ws + 135823360);                    //  8,388,608 B
  float* attn = (float*)(ws + 144211968);                     //  1,048,576 B
  unsigned short* Weff = (unsigned short*)(ws + 145260544);   //  4,194,304 B
  // total: 149,454,848 B

  // K1: casts
  cast_kernel<<<2048, 256, 0, stream>>>((const float4v*)x, (u16x4*)Xbf,
                                        NB * NN * NC / 4);
  cast_kernel<<<768, 256, 0, stream>>>((const float4v*)Wqkv, (u16x4*)Wbf,
                                       3 * NC * NC / 4);
  // K2: qkv projection (writes v row-major, q/k transposed per (b,h,e))
  qkv_gemm<<<dim3(256, 12), 256, 0, stream>>>(Xbf, Wbf, vbf, qkT);
  // K3: L2 norms (sum of squares along n)
  sumsq_kernel<<<8192, 256, 0, stream>>>(qkT, sumsq);
  // K4: gram matrices, split-K partials
  gram_kernel<<<dim3(64, 8), 256, 0, stream>>>(qkT, Spart);
  // K5a: reduce partials + normalize + softmax
  softmax_kernel<<<64, 256, 0, stream>>>(Spart, sumsq, temp, attn);
  // K5b: fold attention into projection weights
  weff_kernel<<<dim3(64, 8), 256, 0, stream>>>(attn, Wproj, Weff);
  // K6: final output GEMM with bias
  out_gemm<<<dim3(32, 4, 8), 256, 0, stream>>>(vbf, Weff, bproj, out);
}

// Round 2
// 158.153 us; speedup vs baseline: 1.1143x; 1.1143x over previous
//
#include <hip/hip_runtime.h>
#include <stdint.h>

#define DEVI __device__ __forceinline__

typedef __attribute__((ext_vector_type(8))) short bf16x8;
typedef __attribute__((ext_vector_type(4))) float f32x4;
typedef __attribute__((ext_vector_type(4))) unsigned short u16x4;
typedef __attribute__((ext_vector_type(4))) float float4v;

static constexpr int NB = 8;      // batch
static constexpr int NN = 4096;   // tokens
static constexpr int NC = 512;    // channels

DEVI unsigned short f2bf(float f) {
  unsigned int u = __builtin_bit_cast(unsigned int, f);
  u += 0x7FFFu + ((u >> 16) & 1u);
  return (unsigned short)(u >> 16);
}
DEVI float bf2f(short s) {
  unsigned int u = ((unsigned int)(unsigned short)s) << 16;
  return __builtin_bit_cast(float, u);
}
DEVI void gload16(const unsigned short* g, unsigned short* l) {
  __builtin_amdgcn_global_load_lds(
      (const __attribute__((address_space(1))) unsigned int*)g,
      (__attribute__((address_space(3))) unsigned int*)l, 16, 0, 0);
}

// ---------------- K1: f32 -> bf16 cast (x) ----------------
__global__ void cast_kernel(const float4v* __restrict__ src,
                            u16x4* __restrict__ dst, int n4) {
  int stride = gridDim.x * blockDim.x;
  for (int i = blockIdx.x * blockDim.x + threadIdx.x; i < n4; i += stride) {
    float4v f = src[i];
    u16x4 o;
    o.x = f2bf(f.x); o.y = f2bf(f.y); o.z = f2bf(f.z); o.w = f2bf(f.w);
    dst[i] = o;
  }
}

// ---------------- K1b: cast W_qk rows + transpose-cast Wv ----------------
// blocks 0..255: cast Wqkv[0:1024][512] -> Wqk bf16
// blocks 256..319: transpose Wqkv[1024:1536] -> WvT[j][k] = Wv[k][j] bf16
__global__ void prep_w(const float* __restrict__ Wqkv,
                       unsigned short* __restrict__ Wqk,
                       unsigned short* __restrict__ WvT) {
  if (blockIdx.x < 256) {
    const float4v* src = (const float4v*)Wqkv;
    u16x4* dst = (u16x4*)Wqk;
    int base = blockIdx.x * 512 + threadIdx.x;
#pragma unroll
    for (int j = 0; j < 2; ++j) {
      int i = base + j * 256;  // < 131072
      float4v f = src[i];
      u16x4 o;
      o.x = f2bf(f.x); o.y = f2bf(f.y); o.z = f2bf(f.z); o.w = f2bf(f.w);
      dst[i] = o;
    }
  } else {
    __shared__ float tls[64][65];
    const int tile = blockIdx.x - 256;       // 0..63
    const int tr = tile >> 3, tc = tile & 7; // tr: k-range, tc: j-range
    const int c = threadIdx.x & 63, rb = threadIdx.x >> 6;
#pragma unroll
    for (int rr = 0; rr < 16; ++rr) {
      int r = rb * 16 + rr;
      tls[r][c] = Wqkv[(size_t)(1024 + tr * 64 + r) * 512 + tc * 64 + c];
    }
    __syncthreads();
#pragma unroll
    for (int rr = 0; rr < 16; ++rr) {
      int j = rb * 16 + rr;
      WvT[(size_t)(tc * 64 + j) * 512 + tr * 64 + c] = f2bf(tls[c][j]);
    }
  }
}

// ---------------- shared GEMM mainloop (128x128 tile, BK=32, K=512) --------
DEVI void gemm_mainloop(const unsigned short* gA, const unsigned short* gB,
                        unsigned short* lA, unsigned short* lB,
                        unsigned short* lAp, unsigned short* lBp,
                        int wr, int wc, int fr, int kg, f32x4 acc[4][4]) {
  for (int kk = 0; kk < 512; kk += 32) {
    gload16(gA + kk, lAp);
    gload16(gA + kk + 64 * 512, lAp + 2048);
    gload16(gB + kk, lBp);
    gload16(gB + kk + 64 * 512, lBp + 2048);
    __syncthreads();
    bf16x8 af[4], bfv[4];
#pragma unroll
    for (int mi = 0; mi < 4; ++mi)
      af[mi] = *(const bf16x8*)&lA[(wr * 64 + mi * 16 + fr) * 32 + kg * 8];
#pragma unroll
    for (int ni = 0; ni < 4; ++ni)
      bfv[ni] = *(const bf16x8*)&lB[(wc * 64 + ni * 16 + fr) * 32 + kg * 8];
#pragma unroll
    for (int mi = 0; mi < 4; ++mi)
#pragma unroll
      for (int ni = 0; ni < 4; ++ni)
        acc[mi][ni] = __builtin_amdgcn_mfma_f32_16x16x32_bf16(
            af[mi], bfv[ni], acc[mi][ni], 0, 0, 0);
    __syncthreads();
  }
}

// ---------------- K2: q/k GEMM -> transposed qkT + sumsq partials ----------
// A = Xbf [32768][512], B = Wqk [1024][512]
// qkT[qrow][n], qrow = t*4096 + b*512 + (h*64+e);  ssPart[32][8192]
__launch_bounds__(256)
__global__ void qk_gemm(const unsigned short* __restrict__ A,
                        const unsigned short* __restrict__ Bw,
                        unsigned short* __restrict__ qkT,
                        float* __restrict__ ssPart) {
  __shared__ __align__(16) unsigned short lA[128 * 32];
  __shared__ __align__(16) unsigned short lB[128 * 32];
  const int tid = threadIdx.x;
  const int wave = tid >> 6, lane = tid & 63;
  const int wr = wave >> 1, wc = wave & 1;
  const int fr = lane & 15, kg = lane >> 4;
  const int rowBase = blockIdx.x * 128;
  const int colBase = blockIdx.y * 128;

  f32x4 acc[4][4] = {};

  const int sRow = wave * 16 + (lane >> 2);
  const int sK = (lane & 3) * 8;
  const unsigned short* gA = A + (size_t)(rowBase + sRow) * 512 + sK;
  const unsigned short* gB = Bw + (size_t)(colBase + sRow) * 512 + sK;
  unsigned short* lAp = lA + wave * 512;
  unsigned short* lBp = lB + wave * 512;

  gemm_mainloop(gA, gB, lA, lB, lAp, lBp, wr, wc, fr, kg, acc);

  const int b = rowBase >> 12;
  const int nb0 = (rowBase & 4095) + wr * 64 + kg * 4;
  float scol[4] = {0.f, 0.f, 0.f, 0.f};
#pragma unroll
  for (int ni = 0; ni < 4; ++ni) {
    const int col = colBase + wc * 64 + ni * 16 + fr;
    const int t = col >> 9, rem = col & 511;
    const size_t qrow = (size_t)(t * 4096 + b * 512 + rem);
#pragma unroll
    for (int mi = 0; mi < 4; ++mi) {
      f32x4 v = acc[mi][ni];
      u16x4 o;
      o.x = f2bf(v[0]); o.y = f2bf(v[1]); o.z = f2bf(v[2]); o.w = f2bf(v[3]);
      *(u16x4*)&qkT[qrow * 4096 + nb0 + mi * 16] = o;
      scol[ni] += v[0] * v[0] + v[1] * v[1] + v[2] * v[2] + v[3] * v[3];
    }
  }
  // deterministic per-block sumsq partial: reduce 8 lanes (wr,kg) per column
  float* ss = (float*)lA;  // 4KB of the 8KB LDS, free after mainloop
#pragma unroll
  for (int ni = 0; ni < 4; ++ni)
    ss[(((ni * 2 + wc) * 16 + fr) << 3) + wr * 4 + kg] = scol[ni];
  __syncthreads();
  if (tid < 128) {
    float s = 0.f;
#pragma unroll
    for (int i = 0; i < 8; ++i) s += ss[(tid << 3) + i];
    const int ni = tid >> 5, wc2 = (tid >> 4) & 1, fr2 = tid & 15;
    const int col = colBase + wc2 * 64 + ni * 16 + fr2;
    const int t = col >> 9, rem = col & 511;
    const int chunk = blockIdx.x & 31;
    ssPart[(size_t)chunk * 8192 + t * 4096 + b * 512 + rem] = s;
  }
}

// ---------------- K3: gram S = q^T k per (b,h), split-K partials -----------
__launch_bounds__(256)
__global__ void gram_kernel(const unsigned short* __restrict__ qkT,
                            float* __restrict__ Spart) {
  const int bh = blockIdx.x;     // 0..63
  const int chunk = blockIdx.y;  // 0..7
  const int b = bh >> 3, h = bh & 7;
  const unsigned short* qbase = qkT + (size_t)(b * 512 + h * 64) * 4096;
  const unsigned short* kbase = qkT + (size_t)(4096 + b * 512 + h * 64) * 4096;
  const int wave = threadIdx.x >> 6, lane = threadIdx.x & 63;
  const int wr = wave >> 1, wc = wave & 1;
  const int fr = lane & 15, kg = lane >> 4;
  f32x4 acc[2][2] = {};
  const int k0 = chunk * 512;
  for (int kk = k0; kk < k0 + 512; kk += 32) {
    bf16x8 a[2], bb[2];
#pragma unroll
    for (int mi = 0; mi < 2; ++mi)
      a[mi] = *(const bf16x8*)(qbase + (size_t)(wr * 32 + mi * 16 + fr) * 4096 + kk + kg * 8);
#pragma unroll
    for (int ni = 0; ni < 2; ++ni)
      bb[ni] = *(const bf16x8*)(kbase + (size_t)(wc * 32 + ni * 16 + fr) * 4096 + kk + kg * 8);
#pragma unroll
    for (int mi = 0; mi < 2; ++mi)
#pragma unroll
      for (int ni = 0; ni < 2; ++ni)
        acc[mi][ni] = __builtin_amdgcn_mfma_f32_16x16x32_bf16(a[mi], bb[ni], acc[mi][ni], 0, 0, 0);
  }
  float* Sp = Spart + ((size_t)chunk * 64 + bh) * 4096;
#pragma unroll
  for (int mi = 0; mi < 2; ++mi)
#pragma unroll
    for (int ni = 0; ni < 2; ++ni) {
      f32x4 v = acc[mi][ni];
#pragma unroll
      for (int r = 0; r < 4; ++r)
        Sp[(wr * 32 + mi * 16 + kg * 4 + r) * 64 + wc * 32 + ni * 16 + fr] = v[r];
    }
}

// ---------------- K4: sumsq reduce + normalize + softmax over d ------------
__global__ void softmax_kernel(const float* __restrict__ Spart,
                               const float* __restrict__ ssPart,
                               const float* __restrict__ temp,
                               float* __restrict__ attnOut) {
  const int bh = blockIdx.x;
  const int b = bh >> 3, h = bh & 7;
  const float tmp = temp[h];
  __shared__ float invq[64], invk[64];
  const int t = threadIdx.x;
  if (t < 128) {
    const int qrow = (t >> 6) * 4096 + b * 512 + h * 64 + (t & 63);
    float s = 0.f;
#pragma unroll
    for (int c2 = 0; c2 < 32; ++c2) s += ssPart[(size_t)c2 * 8192 + qrow];
    float inv = 1.f / fmaxf(sqrtf(s), 1e-12f);
    if (t < 64) invq[t] = inv;
    else invk[t - 64] = inv;
  }
  __syncthreads();
  const int c = t >> 2, q4 = t & 3;
  float lg[16];
  float mx = -1e30f;
#pragma unroll
  for (int j = 0; j < 16; ++j) {
    const int d = q4 * 16 + j;
    float s = 0.f;
#pragma unroll
    for (int ch = 0; ch < 8; ++ch)
      s += Spart[((size_t)ch * 64 + bh) * 4096 + c * 64 + d];
    lg[j] = s * invq[c] * invk[d] * tmp;
    mx = fmaxf(mx, lg[j]);
  }
  mx = fmaxf(mx, __shfl_xor(mx, 1));
  mx = fmaxf(mx, __shfl_xor(mx, 2));
  float sum = 0.f;
#pragma unroll
  for (int j = 0; j < 16; ++j) {
    lg[j] = __expf(lg[j] - mx);
    sum += lg[j];
  }
  sum += __shfl_xor(sum, 1);
  sum += __shfl_xor(sum, 2);
  const float inv = 1.f / sum;
#pragma unroll
  for (int j = 0; j < 16; ++j)
    attnOut[(size_t)bh * 4096 + c * 64 + q4 * 16 + j] = lg[j] * inv;
}

// ---------------- K5: Weff[b][:,h-block] = Wproj[:,h-block] @ attn ---------
__global__ void weff_kernel(const float* __restrict__ attn,
                            const float* __restrict__ Wproj,
                            unsigned short* __restrict__ Weff) {
  const int bh = blockIdx.x, eb = blockIdx.y;
  const int b = bh >> 3, h = bh & 7;
  __shared__ float at[64 * 64];
  for (int i = threadIdx.x; i < 4096; i += 256)
    at[i] = attn[(size_t)bh * 4096 + i];
  __syncthreads();
  const int e = eb * 64 + (threadIdx.x >> 2);
  const int dq = threadIdx.x & 3;
  float acc[16] = {};
  const float* wrow = Wproj + (size_t)e * 512 + h * 64;
  for (int c = 0; c < 64; ++c) {
    const float w = wrow[c];
#pragma unroll
    for (int j = 0; j < 16; ++j) acc[j] += w * at[c * 64 + dq * 16 + j];
  }
  unsigned short* outp = Weff + ((size_t)b * 512 + e) * 512 + h * 64 + dq * 16;
#pragma unroll
  for (int j = 0; j < 16; ++j) outp[j] = f2bf(acc[j]);
}

// ---------------- K6: Wcomb[b] = Weff[b] @ Wv  (= Weff · WvT^T) ------------
__launch_bounds__(256)
__global__ void wcomb_gemm(const unsigned short* __restrict__ WeffAll,
                           const unsigned short* __restrict__ WvT,
                           unsigned short* __restrict__ WcombAll) {
  __shared__ __align__(16) unsigned short lA[128 * 32];
  __shared__ __align__(16) unsigned short lB[128 * 32];
  const int tid = threadIdx.x;
  const int wave = tid >> 6, lane = tid & 63;
  const int wr = wave >> 1, wc = wave & 1;
  const int fr = lane & 15, kg = lane >> 4;
  const int b = blockIdx.z;
  const int rowBase = blockIdx.x * 128;
  const int colBase = blockIdx.y * 128;
  const unsigned short* A = WeffAll + (size_t)b * 512 * 512;

  f32x4 acc[4][4] = {};
  const int sRow = wave * 16 + (lane >> 2);
  const int sK = (lane & 3) * 8;
  const unsigned short* gA = A + (size_t)(rowBase + sRow) * 512 + sK;
  const unsigned short* gB = WvT + (size_t)(colBase + sRow) * 512 + sK;
  unsigned short* lAp = lA + wave * 512;
  unsigned short* lBp = lB + wave * 512;

  gemm_mainloop(gA, gB, lA, lB, lAp, lBp, wr, wc, fr, kg, acc);

  unsigned short* Wc = WcombAll + (size_t)b * 512 * 512;
#pragma unroll
  for (int mi = 0; mi < 4; ++mi) {
    const int rbase = rowBase + wr * 64 + mi * 16 + kg * 4;
#pragma unroll
    for (int ni = 0; ni < 4; ++ni) {
      const int col = colBase + wc * 64 + ni * 16 + fr;
      f32x4 v = acc[mi][ni];
#pragma unroll
      for (int r = 0; r < 4; ++r)
        Wc[(size_t)(rbase + r) * 512 + col] = f2bf(v[r]);
    }
  }
}

// ---------------- K7: final = x @ Wcomb[b]^T + bproj -----------------------
__launch_bounds__(256)
__global__ void out_gemm(const unsigned short* __restrict__ Xbf,
                         const unsigned short* __restrict__ WcombAll,
                         const float* __restrict__ bias,
                         float* __restrict__ out) {
  __shared__ __align__(16) unsigned short lA[128 * 32];
  __shared__ __align__(16) unsigned short lB[128 * 32];
  const int tid = threadIdx.x;
  const int wave = tid >> 6, lane = tid & 63;
  const int wr = wave >> 1, wc = wave & 1;
  const int fr = lane & 15, kg = lane >> 4;
  const int b = blockIdx.z;
  const int rowBase = blockIdx.x * 128;  // within b
  const int colBase = blockIdx.y * 128;
  const unsigned short* A = Xbf + (size_t)b * 4096 * 512;
  const unsigned short* Bw = WcombAll + (size_t)b * 512 * 512;

  f32x4 acc[4][4] = {};
  const int sRow = wave * 16 + (lane >> 2);
  const int sK = (lane & 3) * 8;
  const unsigned short* gA = A + (size_t)(rowBase + sRow) * 512 + sK;
  const unsigned short* gB = Bw + (size_t)(colBase + sRow) * 512 + sK;
  unsigned short* lAp = lA + wave * 512;
  unsigned short* lBp = lB + wave * 512;

  gemm_mainloop(gA, gB, lA, lB, lAp, lBp, wr, wc, fr, kg, acc);

#pragma unroll
  for (int mi = 0; mi < 4; ++mi) {
    const int rbase = rowBase + wr * 64 + mi * 16 + kg * 4;
#pragma unroll
    for (int ni = 0; ni < 4; ++ni) {
      const int col = colBase + wc * 64 + ni * 16 + fr;
      const float bcol = bias[col];
      f32x4 v = acc[mi][ni];
#pragma unroll
      for (int r = 0; r < 4; ++r)
        out[((size_t)b * 4096 + rbase + r) * 512 + col] = v[r] + bcol;
    }
  }
}

extern "C" void kernel_launch(void* const* d_in, const int* in_sizes, int n_in,
                              void* d_out, int out_size, void* d_ws, size_t ws_size,
                              hipStream_t stream) {
  const float* x = (const float*)d_in[0];      // [8][4096][512]
  const float* Wqkv = (const float*)d_in[1];   // [1536][512]
  const float* Wproj = (const float*)d_in[2];  // [512][512]
  const float* bproj = (const float*)d_in[3];  // [512]
  const float* temp = (const float*)d_in[4];   // [8]
  float* out = (float*)d_out;

  char* ws = (char*)d_ws;
  unsigned short* Xbf = (unsigned short*)(ws + 0);            // 33,554,432 B
  unsigned short* Wqk = (unsigned short*)(ws + 33554432);     //  1,048,576 B
  unsigned short* WvT = (unsigned short*)(ws + 34603008);     //    524,288 B
  unsigned short* qkT = (unsigned short*)(ws + 35127296);     // 67,108,864 B
  float* ssPart = (float*)(ws + 102236160);                   //  1,048,576 B
  float* Spart = (float*)(ws + 103284736);                    //  8,388,608 B
  float* attn = (float*)(ws + 111673344);                     //  1,048,576 B
  unsigned short* Weff = (unsigned short*)(ws + 112721920);   //  4,194,304 B
  unsigned short* Wcomb = (unsigned short*)(ws + 116916224);  //  4,194,304 B
  // total: 121,110,528 B

  // K1: cast x
  cast_kernel<<<2048, 256, 0, stream>>>((const float4v*)x, (u16x4*)Xbf,
                                        NB * NN * NC / 4);
  // K1b: cast W_qk + transpose-cast Wv
  prep_w<<<320, 256, 0, stream>>>(Wqkv, Wqk, WvT);
  // K2: q/k projection (transposed write + sumsq partials)
  qk_gemm<<<dim3(256, 8), 256, 0, stream>>>(Xbf, Wqk, qkT, ssPart);
  // K3: gram matrices, split-K partials
  gram_kernel<<<dim3(64, 8), 256, 0, stream>>>(qkT, Spart);
  // K4: reduce partials + normalize + softmax
  softmax_kernel<<<64, 256, 0, stream>>>(Spart, ssPart, temp, attn);
  // K5: fold attention into projection weights
  weff_kernel<<<dim3(64, 8), 256, 0, stream>>>(attn, Wproj, Weff);
  // K6: Wcomb[b] = Weff[b] @ Wv
  wcomb_gemm<<<dim3(4, 4, 8), 256, 0, stream>>>(Weff, WvT, Wcomb);
  // K7: final = x @ Wcomb^T + bias
  out_gemm<<<dim3(32, 4, 8), 256, 0, stream>>>(Xbf, Wcomb, bproj, out);
}

// Round 3
// 148.521 us; speedup vs baseline: 1.1865x; 1.0649x over previous
//
#include <hip/hip_runtime.h>
#include <stdint.h>

#define DEVI __device__ __forceinline__

typedef __attribute__((ext_vector_type(8))) short bf16x8;
typedef __attribute__((ext_vector_type(4))) float f32x4;
typedef __attribute__((ext_vector_type(4))) unsigned short u16x4;
typedef __attribute__((ext_vector_type(4))) float float4v;

DEVI unsigned short f2bf(float f) {
  unsigned int u = __builtin_bit_cast(unsigned int, f);
  u += 0x7FFFu + ((u >> 16) & 1u);
  return (unsigned short)(u >> 16);
}
DEVI float bf2f(short s) {
  unsigned int u = ((unsigned int)(unsigned short)s) << 16;
  return __builtin_bit_cast(float, u);
}
DEVI void gload16(const unsigned short* g, unsigned short* l) {
  __builtin_amdgcn_global_load_lds(
      (const __attribute__((address_space(1))) unsigned int*)g,
      (__attribute__((address_space(3))) unsigned int*)l, 16, 0, 0);
}

// ---------------- K1: x -> Xbf (row-major) + xT (transposed), one pass -----
__global__ void cast_both(const float* __restrict__ x,
                          unsigned short* __restrict__ Xbf,
                          unsigned short* __restrict__ xT) {
  __shared__ float tls[64][65];
  const int n0 = blockIdx.x * 64, c0 = blockIdx.y * 64, b = blockIdx.z;
  const int c = threadIdx.x & 63, rb = threadIdx.x >> 6;
#pragma unroll
  for (int rr = 0; rr < 16; ++rr) {
    int r = rb * 16 + rr;
    float v = x[((size_t)b * 4096 + n0 + r) * 512 + c0 + c];
    tls[r][c] = v;
    Xbf[((size_t)b * 4096 + n0 + r) * 512 + c0 + c] = f2bf(v);
  }
  __syncthreads();
#pragma unroll
  for (int rr = 0; rr < 16; ++rr) {
    int j = rb * 16 + rr;
    xT[((size_t)b * 512 + c0 + j) * 4096 + n0 + c] = f2bf(tls[c][j]);
  }
}

// ---------------- K1b: cast W_qk rows + transpose-cast Wv ----------------
__global__ void prep_w(const float* __restrict__ Wqkv,
                       unsigned short* __restrict__ Wqk,
                       unsigned short* __restrict__ WvT) {
  if (blockIdx.x < 256) {
    const float4v* src = (const float4v*)Wqkv;
    u16x4* dst = (u16x4*)Wqk;
    int base = blockIdx.x * 512 + threadIdx.x;
#pragma unroll
    for (int j = 0; j < 2; ++j) {
      int i = base + j * 256;
      float4v f = src[i];
      u16x4 o;
      o.x = f2bf(f.x); o.y = f2bf(f.y); o.z = f2bf(f.z); o.w = f2bf(f.w);
      dst[i] = o;
    }
  } else {
    __shared__ float tls[64][65];
    const int tile = blockIdx.x - 256;
    const int tr = tile >> 3, tc = tile & 7;
    const int c = threadIdx.x & 63, rb = threadIdx.x >> 6;
#pragma unroll
    for (int rr = 0; rr < 16; ++rr) {
      int r = rb * 16 + rr;
      tls[r][c] = Wqkv[(size_t)(1024 + tr * 64 + r) * 512 + tc * 64 + c];
    }
    __syncthreads();
#pragma unroll
    for (int rr = 0; rr < 16; ++rr) {
      int j = rb * 16 + rr;
      WvT[(size_t)(tc * 64 + j) * 512 + tr * 64 + c] = f2bf(tls[c][j]);
    }
  }
}

// ---------------- shared GEMM mainloop (128x128 tile, BK=32) ---------------
template <int STRIDE, int KITERS>
DEVI void gemm_mainloop(const unsigned short* gA, const unsigned short* gB,
                        unsigned short* lA, unsigned short* lB,
                        unsigned short* lAp, unsigned short* lBp,
                        int wr, int wc, int fr, int kg, f32x4 acc[4][4]) {
  for (int kk = 0; kk < KITERS * 32; kk += 32) {
    gload16(gA + kk, lAp);
    gload16(gA + kk + (size_t)64 * STRIDE, lAp + 2048);
    gload16(gB + kk, lBp);
    gload16(gB + kk + (size_t)64 * STRIDE, lBp + 2048);
    __syncthreads();
    bf16x8 af[4], bfv[4];
#pragma unroll
    for (int mi = 0; mi < 4; ++mi)
      af[mi] = *(const bf16x8*)&lA[(wr * 64 + mi * 16 + fr) * 32 + kg * 8];
#pragma unroll
    for (int ni = 0; ni < 4; ++ni)
      bfv[ni] = *(const bf16x8*)&lB[(wc * 64 + ni * 16 + fr) * 32 + kg * 8];
#pragma unroll
    for (int mi = 0; mi < 4; ++mi)
#pragma unroll
      for (int ni = 0; ni < 4; ++ni)
        acc[mi][ni] = __builtin_amdgcn_mfma_f32_16x16x32_bf16(
            af[mi], bfv[ni], acc[mi][ni], 0, 0, 0);
    __syncthreads();
  }
}

// ---------------- K2: G_b = xT_b @ xT_b^T  (split-K over n) ----------------
__launch_bounds__(256)
__global__ void gsyrk(const unsigned short* __restrict__ xT,
                      float* __restrict__ Gpart) {
  __shared__ __align__(16) unsigned short lA[128 * 32];
  __shared__ __align__(16) unsigned short lB[128 * 32];
  const int tid = threadIdx.x, wave = tid >> 6, lane = tid & 63;
  const int wr = wave >> 1, wc = wave & 1, fr = lane & 15, kg = lane >> 4;
  const int tc = blockIdx.x >> 2, td = blockIdx.x & 3;
  const int chunk = blockIdx.y, b = blockIdx.z;
  const unsigned short* xb = xT + (size_t)b * 512 * 4096 + chunk * 1024;
  f32x4 acc[4][4] = {};
  const int sRow = wave * 16 + (lane >> 2);
  const int sK = (lane & 3) * 8;
  const unsigned short* gA = xb + (size_t)(tc * 128 + sRow) * 4096 + sK;
  const unsigned short* gB = xb + (size_t)(td * 128 + sRow) * 4096 + sK;
  gemm_mainloop<4096, 32>(gA, gB, lA, lB, lA + wave * 512, lB + wave * 512,
                          wr, wc, fr, kg, acc);
  float* Gp = Gpart + (size_t)(chunk * 8 + b) * 512 * 512;
#pragma unroll
  for (int mi = 0; mi < 4; ++mi) {
    const int rbase = tc * 128 + wr * 64 + mi * 16 + kg * 4;
#pragma unroll
    for (int ni = 0; ni < 4; ++ni) {
      const int col = td * 128 + wc * 64 + ni * 16 + fr;
      f32x4 v = acc[mi][ni];
#pragma unroll
      for (int r = 0; r < 4; ++r)
        Gp[(size_t)(rbase + r) * 512 + col] = v[r];
    }
  }
}

// ---------------- K3: reduce split-K partials -> G bf16 --------------------
__global__ void greduce(const float* __restrict__ Gpart,
                        unsigned short* __restrict__ Gbf) {
  const int stride = gridDim.x * blockDim.x;
  const int n4 = 8 * 512 * 512 / 4;
  for (int i = blockIdx.x * blockDim.x + threadIdx.x; i < n4; i += stride) {
    float4v s = ((const float4v*)Gpart)[i];
#pragma unroll
    for (int c = 1; c < 4; ++c) {
      float4v t = ((const float4v*)(Gpart + (size_t)c * 8 * 512 * 512))[i];
      s.x += t.x; s.y += t.y; s.z += t.z; s.w += t.w;
    }
    u16x4 o;
    o.x = f2bf(s.x); o.y = f2bf(s.y); o.z = f2bf(s.z); o.w = f2bf(s.w);
    ((u16x4*)Gbf)[i] = o;
  }
}

// ---------------- K4: T_b = Wqk @ G_b (+ fused sumsq partials) -------------
__launch_bounds__(256)
__global__ void tall_gemm(const unsigned short* __restrict__ Wqk,
                          const unsigned short* __restrict__ Gbf,
                          unsigned short* __restrict__ Tbf,
                          float* __restrict__ ssPart) {
  __shared__ __align__(16) unsigned short lA[128 * 32];
  __shared__ __align__(16) unsigned short lB[128 * 32];
  __shared__ float ssL[128][2];
  const int tid = threadIdx.x, wave = tid >> 6, lane = tid & 63;
  const int wr = wave >> 1, wc = wave & 1, fr = lane & 15, kg = lane >> 4;
  const int rowBase = blockIdx.x * 128, colBase = blockIdx.y * 128;
  const int b = blockIdx.z;
  const unsigned short* Gb = Gbf + (size_t)b * 512 * 512;
  f32x4 acc[4][4] = {};
  const int sRow = wave * 16 + (lane >> 2);
  const int sK = (lane & 3) * 8;
  gemm_mainloop<512, 16>(Wqk + (size_t)(rowBase + sRow) * 512 + sK,
                         Gb + (size_t)(colBase + sRow) * 512 + sK,
                         lA, lB, lA + wave * 512, lB + wave * 512,
                         wr, wc, fr, kg, acc);
  unsigned short* Tb = Tbf + (size_t)b * 1024 * 512;
#pragma unroll
  for (int mi = 0; mi < 4; ++mi) {
    const int rbase = rowBase + wr * 64 + mi * 16 + kg * 4;
    f32x4 sacc = {0.f, 0.f, 0.f, 0.f};
#pragma unroll
    for (int ni = 0; ni < 4; ++ni) {
      const int col = colBase + wc * 64 + ni * 16 + fr;
      f32x4 v = acc[mi][ni];
#pragma unroll
      for (int r = 0; r < 4; ++r) {
        float w = bf2f((short)Wqk[(size_t)(rbase + r) * 512 + col]);
        Tb[(size_t)(rbase + r) * 512 + col] = f2bf(v[r]);
        sacc[r] += v[r] * w;
      }
    }
#pragma unroll
    for (int o = 1; o < 16; o <<= 1) {
#pragma unroll
      for (int r = 0; r < 4; ++r) sacc[r] += __shfl_xor(sacc[r], o);
    }
    if (fr == 0) {
#pragma unroll
      for (int r = 0; r < 4; ++r)
        ssL[wr * 64 + mi * 16 + kg * 4 + r][wc] = sacc[r];
    }
  }
  __syncthreads();
  if (tid < 128)
    ssPart[((size_t)blockIdx.y * 8 + b) * 1024 + rowBase + tid] =
        ssL[tid][0] + ssL[tid][1];
}

// ---------------- K5: S[b,h] = T_q(h) @ Wk(h)^T ----------------------------
__launch_bounds__(256)
__global__ void sgemm(const unsigned short* __restrict__ Tbf,
                      const unsigned short* __restrict__ Wqk,
                      float* __restrict__ Sraw) {
  const int bh = blockIdx.x, b = bh >> 3, h = bh & 7;
  const unsigned short* qbase = Tbf + (size_t)(b * 1024 + h * 64) * 512;
  const unsigned short* kbase = Wqk + (size_t)(512 + h * 64) * 512;
  const int wave = threadIdx.x >> 6, lane = threadIdx.x & 63;
  const int wr = wave >> 1, wc = wave & 1, fr = lane & 15, kg = lane >> 4;
  f32x4 acc[2][2] = {};
  for (int kk = 0; kk < 512; kk += 32) {
    bf16x8 a[2], bb[2];
#pragma unroll
    for (int mi = 0; mi < 2; ++mi)
      a[mi] = *(const bf16x8*)(qbase + (size_t)(wr * 32 + mi * 16 + fr) * 512 + kk + kg * 8);
#pragma unroll
    for (int ni = 0; ni < 2; ++ni)
      bb[ni] = *(const bf16x8*)(kbase + (size_t)(wc * 32 + ni * 16 + fr) * 512 + kk + kg * 8);
#pragma unroll
    for (int mi = 0; mi < 2; ++mi)
#pragma unroll
      for (int ni = 0; ni < 2; ++ni)
        acc[mi][ni] = __builtin_amdgcn_mfma_f32_16x16x32_bf16(a[mi], bb[ni], acc[mi][ni], 0, 0, 0);
  }
  float* Sp = Sraw + (size_t)bh * 4096;
#pragma unroll
  for (int mi = 0; mi < 2; ++mi)
#pragma unroll
    for (int ni = 0; ni < 2; ++ni) {
      f32x4 v = acc[mi][ni];
#pragma unroll
      for (int r = 0; r < 4; ++r)
        Sp[(wr * 32 + mi * 16 + kg * 4 + r) * 64 + wc * 32 + ni * 16 + fr] = v[r];
    }
}

// ---------------- K6: sumsq reduce + normalize + softmax over d ------------
__global__ void softmax_kernel(const float* __restrict__ Sraw,
                               const float* __restrict__ ssPart,
                               const float* __restrict__ temp,
                               float* __restrict__ attnOut) {
  const int bh = blockIdx.x;
  const int b = bh >> 3, h = bh & 7;
  const float tmp = temp[h];
  __shared__ float invq[64], invk[64];
  const int t = threadIdx.x;
  if (t < 128) {
    const int r = (t >> 6) * 512 + h * 64 + (t & 63);
    float s = 0.f;
#pragma unroll
    for (int nt = 0; nt < 4; ++nt) s += ssPart[((size_t)nt * 8 + b) * 1024 + r];
    float inv = 1.f / fmaxf(sqrtf(s), 1e-12f);
    if (t < 64) invq[t] = inv;
    else invk[t - 64] = inv;
  }
  __syncthreads();
  const int c = t >> 2, q4 = t & 3;
  float lg[16];
  float mx = -1e30f;
#pragma unroll
  for (int j = 0; j < 16; ++j) {
    const int d = q4 * 16 + j;
    float s = Sraw[(size_t)bh * 4096 + c * 64 + d];
    lg[j] = s * invq[c] * invk[d] * tmp;
    mx = fmaxf(mx, lg[j]);
  }
  mx = fmaxf(mx, __shfl_xor(mx, 1));
  mx = fmaxf(mx, __shfl_xor(mx, 2));
  float sum = 0.f;
#pragma unroll
  for (int j = 0; j < 16; ++j) {
    lg[j] = __expf(lg[j] - mx);
    sum += lg[j];
  }
  sum += __shfl_xor(sum, 1);
  sum += __shfl_xor(sum, 2);
  const float inv = 1.f / sum;
#pragma unroll
  for (int j = 0; j < 16; ++j)
    attnOut[(size_t)bh * 4096 + c * 64 + q4 * 16 + j] = lg[j] * inv;
}

// ---------------- K7: Weff[b][:,h-block] = Wproj[:,h-block] @ attn ---------
__global__ void weff_kernel(const float* __restrict__ attn,
                            const float* __restrict__ Wproj,
                            unsigned short* __restrict__ Weff) {
  const int bh = blockIdx.x, eb = blockIdx.y;
  const int b = bh >> 3, h = bh & 7;
  __shared__ float at[64 * 64];
  for (int i = threadIdx.x; i < 4096; i += 256)
    at[i] = attn[(size_t)bh * 4096 + i];
  __syncthreads();
  const int e = eb * 64 + (threadIdx.x >> 2);
  const int dq = threadIdx.x & 3;
  float acc[16] = {};
  const float* wrow = Wproj + (size_t)e * 512 + h * 64;
  for (int c = 0; c < 64; ++c) {
    const float w = wrow[c];
#pragma unroll
    for (int j = 0; j < 16; ++j) acc[j] += w * at[c * 64 + dq * 16 + j];
  }
  unsigned short* outp = Weff + ((size_t)b * 512 + e) * 512 + h * 64 + dq * 16;
#pragma unroll
  for (int j = 0; j < 16; ++j) outp[j] = f2bf(acc[j]);
}

// ---------------- K8: Wcomb[b] = Weff[b] @ Wv  (= Weff · WvT^T) ------------
__launch_bounds__(256)
__global__ void wcomb_gemm(const unsigned short* __restrict__ WeffAll,
                           const unsigned short* __restrict__ WvT,
                           unsigned short* __restrict__ WcombAll) {
  __shared__ __align__(16) unsigned short lA[128 * 32];
  __shared__ __align__(16) unsigned short lB[128 * 32];
  const int tid = threadIdx.x, wave = tid >> 6, lane = tid & 63;
  const int wr = wave >> 1, wc = wave & 1, fr = lane & 15, kg = lane >> 4;
  const int b = blockIdx.z;
  const int rowBase = blockIdx.x * 128, colBase = blockIdx.y * 128;
  const unsigned short* A = WeffAll + (size_t)b * 512 * 512;
  f32x4 acc[4][4] = {};
  const int sRow = wave * 16 + (lane >> 2);
  const int sK = (lane & 3) * 8;
  gemm_mainloop<512, 16>(A + (size_t)(rowBase + sRow) * 512 + sK,
                         WvT + (size_t)(colBase + sRow) * 512 + sK,
                         lA, lB, lA + wave * 512, lB + wave * 512,
                         wr, wc, fr, kg, acc);
  unsigned short* Wc = WcombAll + (size_t)b * 512 * 512;
#pragma unroll
  for (int mi = 0; mi < 4; ++mi) {
    const int rbase = rowBase + wr * 64 + mi * 16 + kg * 4;
#pragma unroll
    for (int ni = 0; ni < 4; ++ni) {
      const int col = colBase + wc * 64 + ni * 16 + fr;
      f32x4 v = acc[mi][ni];
#pragma unroll
      for (int r = 0; r < 4; ++r)
        Wc[(size_t)(rbase + r) * 512 + col] = f2bf(v[r]);
    }
  }
}

// ---------------- K9: final = x @ Wcomb[b]^T + bproj -----------------------
__launch_bounds__(256)
__global__ void out_gemm(const unsigned short* __restrict__ Xbf,
                         const unsigned short* __restrict__ WcombAll,
                         const float* __restrict__ bias,
                         float* __restrict__ out) {
  __shared__ __align__(16) unsigned short lA[128 * 32];
  __shared__ __align__(16) unsigned short lB[128 * 32];
  const int tid = threadIdx.x, wave = tid >> 6, lane = tid & 63;
  const int wr = wave >> 1, wc = wave & 1, fr = lane & 15, kg = lane >> 4;
  const int b = blockIdx.z;
  const int rowBase = blockIdx.x * 128, colBase = blockIdx.y * 128;
  const unsigned short* A = Xbf + (size_t)b * 4096 * 512;
  const unsigned short* Bw = WcombAll + (size_t)b * 512 * 512;
  f32x4 acc[4][4] = {};
  const int sRow = wave * 16 + (lane >> 2);
  const int sK = (lane & 3) * 8;
  gemm_mainloop<512, 16>(A + (size_t)(rowBase + sRow) * 512 + sK,
                         Bw + (size_t)(colBase + sRow) * 512 + sK,
                         lA, lB, lA + wave * 512, lB + wave * 512,
                         wr, wc, fr, kg, acc);
#pragma unroll
  for (int mi = 0; mi < 4; ++mi) {
    const int rbase = rowBase + wr * 64 + mi * 16 + kg * 4;
#pragma unroll
    for (int ni = 0; ni < 4; ++ni) {
      const int col = colBase + wc * 64 + ni * 16 + fr;
      const float bcol = bias[col];
      f32x4 v = acc[mi][ni];
#pragma unroll
      for (int r = 0; r < 4; ++r)
        out[((size_t)b * 4096 + rbase + r) * 512 + col] = v[r] + bcol;
    }
  }
}

extern "C" void kernel_launch(void* const* d_in, const int* in_sizes, int n_in,
                              void* d_out, int out_size, void* d_ws, size_t ws_size,
                              hipStream_t stream) {
  const float* x = (const float*)d_in[0];      // [8][4096][512]
  const float* Wqkv = (const float*)d_in[1];   // [1536][512]
  const float* Wproj = (const float*)d_in[2];  // [512][512]
  const float* bproj = (const float*)d_in[3];  // [512]
  const float* temp = (const float*)d_in[4];   // [8]
  float* out = (float*)d_out;

  char* ws = (char*)d_ws;
  unsigned short* Xbf = (unsigned short*)(ws + 0);            // 33,554,432
  unsigned short* xT = (unsigned short*)(ws + 33554432);      // 33,554,432
  unsigned short* Wqk = (unsigned short*)(ws + 67108864);     //  1,048,576
  unsigned short* WvT = (unsigned short*)(ws + 68157440);     //    524,288
  float* Gpart = (float*)(ws + 68681728);                     // 33,554,432
  unsigned short* Gbf = (unsigned short*)(ws + 102236160);    //  4,194,304
  unsigned short* Tbf = (unsigned short*)(ws + 106430464);    //  8,388,608
  float* ssPart = (float*)(ws + 114819072);                   //    131,072
  float* Sraw = (float*)(ws + 114950144);                     //  1,048,576
  float* attn = (float*)(ws + 115998720);                     //  1,048,576
  unsigned short* Weff = (unsigned short*)(ws + 117047296);   //  4,194,304
  unsigned short* Wcomb = (unsigned short*)(ws + 121241600);  //  4,194,304
  // total: 125,435,904 B

  cast_both<<<dim3(64, 8, 8), 256, 0, stream>>>(x, Xbf, xT);
  prep_w<<<320, 256, 0, stream>>>(Wqkv, Wqk, WvT);
  gsyrk<<<dim3(16, 4, 8), 256, 0, stream>>>(xT, Gpart);
  greduce<<<1024, 256, 0, stream>>>(Gpart, Gbf);
  tall_gemm<<<dim3(8, 4, 8), 256, 0, stream>>>(Wqk, Gbf, Tbf, ssPart);
  sgemm<<<64, 256, 0, stream>>>(Tbf, Wqk, Sraw);
  softmax_kernel<<<64, 256, 0, stream>>>(Sraw, ssPart, temp, attn);
  weff_kernel<<<dim3(64, 8), 256, 0, stream>>>(attn, Wproj, Weff);
  wcomb_gemm<<<dim3(4, 4, 8), 256, 0, stream>>>(Weff, WvT, Wcomb);
  out_gemm<<<dim3(32, 4, 8), 256, 0, stream>>>(Xbf, Wcomb, bproj, out);
}

// Round 4
// 142.325 us; speedup vs baseline: 1.2382x; 1.0435x over previous
//
#include <hip/hip_runtime.h>
#include <stdint.h>

#define DEVI __device__ __forceinline__

typedef __attribute__((ext_vector_type(8))) short bf16x8;
typedef __attribute__((ext_vector_type(4))) float f32x4;
typedef __attribute__((ext_vector_type(4))) unsigned short u16x4;
typedef __attribute__((ext_vector_type(4))) float float4v;

DEVI unsigned short f2bf(float f) {
  unsigned int u = __builtin_bit_cast(unsigned int, f);
  u += 0x7FFFu + ((u >> 16) & 1u);
  return (unsigned short)(u >> 16);
}
DEVI float bf2f(short s) {
  unsigned int u = ((unsigned int)(unsigned short)s) << 16;
  return __builtin_bit_cast(float, u);
}
DEVI void gload16(const unsigned short* g, unsigned short* l) {
  __builtin_amdgcn_global_load_lds(
      (const __attribute__((address_space(1))) unsigned int*)g,
      (__attribute__((address_space(3))) unsigned int*)l, 16, 0, 0);
}

// ---------------- K1: x -> Xbf + xT, plus weight prep (z==8) ---------------
__global__ void cast_prep(const float* __restrict__ x,
                          unsigned short* __restrict__ Xbf,
                          unsigned short* __restrict__ xT,
                          const float* __restrict__ Wqkv,
                          unsigned short* __restrict__ Wqk,
                          unsigned short* __restrict__ WvT) {
  __shared__ float tls[64][65];
  const int c = threadIdx.x & 63, rb = threadIdx.x >> 6;
  if (blockIdx.z < 8) {
    const int n0 = blockIdx.x * 64, c0 = blockIdx.y * 64, b = blockIdx.z;
#pragma unroll
    for (int rr = 0; rr < 16; ++rr) {
      int r = rb * 16 + rr;
      float v = x[((size_t)b * 4096 + n0 + r) * 512 + c0 + c];
      tls[r][c] = v;
      Xbf[((size_t)b * 4096 + n0 + r) * 512 + c0 + c] = f2bf(v);
    }
    __syncthreads();
#pragma unroll
    for (int rr = 0; rr < 16; ++rr) {
      int j = rb * 16 + rr;
      xT[((size_t)b * 512 + c0 + j) * 4096 + n0 + c] = f2bf(tls[c][j]);
    }
    return;
  }
  const int id = blockIdx.y * 64 + blockIdx.x;
  if (id < 256) {
    const float4v* src = (const float4v*)Wqkv;
    u16x4* dst = (u16x4*)Wqk;
    int base = id * 512 + threadIdx.x;
#pragma unroll
    for (int j = 0; j < 2; ++j) {
      int i = base + j * 256;
      float4v f = src[i];
      u16x4 o;
      o.x = f2bf(f.x); o.y = f2bf(f.y); o.z = f2bf(f.z); o.w = f2bf(f.w);
      dst[i] = o;
    }
  } else if (id < 320) {
    const int tile = id - 256;
    const int tr = tile >> 3, tc = tile & 7;
#pragma unroll
    for (int rr = 0; rr < 16; ++rr) {
      int r = rb * 16 + rr;
      tls[r][c] = Wqkv[(size_t)(1024 + tr * 64 + r) * 512 + tc * 64 + c];
    }
    __syncthreads();
#pragma unroll
    for (int rr = 0; rr < 16; ++rr) {
      int j = rb * 16 + rr;
      WvT[(size_t)(tc * 64 + j) * 512 + tr * 64 + c] = f2bf(tls[c][j]);
    }
  }
}

// ------------- double-buffered GEMM mainloop (128x128 tile, BK=32) ---------
// 2-phase: issue next-tile global_load_lds BEFORE ds_read+MFMA of current;
// one barrier per tile (its implicit vmcnt(0)/lgkmcnt(0) drain lands AFTER
// the MFMA work, so staging overlaps compute).
template <int KITERS>
DEVI void gemm_db(const unsigned short* gA, int strideA,
                  const unsigned short* gB, int strideB,
                  unsigned short (*lA)[4096], unsigned short (*lB)[4096],
                  int wave, int wr, int wc, int fr, int kg, f32x4 acc[4][4]) {
  const int wo = wave * 512;
#define STAGE_T(buf, kk)                                                    \
  gload16(gA + (kk) * 32, lA[buf] + wo);                                    \
  gload16(gA + (kk) * 32 + (size_t)64 * strideA, lA[buf] + wo + 2048);      \
  gload16(gB + (kk) * 32, lB[buf] + wo);                                    \
  gload16(gB + (kk) * 32 + (size_t)64 * strideB, lB[buf] + wo + 2048);
  STAGE_T(0, 0);
  __syncthreads();
  int cur = 0;
  for (int kk = 1; kk <= KITERS; ++kk) {
    if (kk < KITERS) { STAGE_T(cur ^ 1, kk); }
    bf16x8 af[4], bfv[4];
#pragma unroll
    for (int mi = 0; mi < 4; ++mi)
      af[mi] = *(const bf16x8*)&lA[cur][(wr * 64 + mi * 16 + fr) * 32 + kg * 8];
#pragma unroll
    for (int ni = 0; ni < 4; ++ni)
      bfv[ni] = *(const bf16x8*)&lB[cur][(wc * 64 + ni * 16 + fr) * 32 + kg * 8];
#pragma unroll
    for (int mi = 0; mi < 4; ++mi)
#pragma unroll
      for (int ni = 0; ni < 4; ++ni)
        acc[mi][ni] = __builtin_amdgcn_mfma_f32_16x16x32_bf16(
            af[mi], bfv[ni], acc[mi][ni], 0, 0, 0);
    __syncthreads();
    cur ^= 1;
  }
#undef STAGE_T
}

// ---------------- K2: G_b = xT_b @ xT_b^T, upper tile-pairs only -----------
__launch_bounds__(256)
__global__ void gsyrk(const unsigned short* __restrict__ xT,
                      float* __restrict__ Gpart) {
  __shared__ __align__(16) unsigned short lA[2][4096];
  __shared__ __align__(16) unsigned short lB[2][4096];
  static const int PTC[10] = {0, 0, 0, 0, 1, 1, 1, 2, 2, 3};
  static const int PTD[10] = {0, 1, 2, 3, 1, 2, 3, 2, 3, 3};
  const int tid = threadIdx.x, wave = tid >> 6, lane = tid & 63;
  const int wr = wave >> 1, wc = wave & 1, fr = lane & 15, kg = lane >> 4;
  const int tc = PTC[blockIdx.x], td = PTD[blockIdx.x];
  const int chunk = blockIdx.y, b = blockIdx.z;
  const unsigned short* xb = xT + (size_t)b * 512 * 4096 + chunk * 1024;
  f32x4 acc[4][4] = {};
  const int sRow = wave * 16 + (lane >> 2);
  const int sK = (lane & 3) * 8;
  gemm_db<32>(xb + (size_t)(tc * 128 + sRow) * 4096 + sK, 4096,
              xb + (size_t)(td * 128 + sRow) * 4096 + sK, 4096,
              lA, lB, wave, wr, wc, fr, kg, acc);
  float* Gp = Gpart + (size_t)(chunk * 8 + b) * 512 * 512;
#pragma unroll
  for (int mi = 0; mi < 4; ++mi) {
    const int rIT = wr * 64 + mi * 16 + kg * 4;
#pragma unroll
    for (int ni = 0; ni < 4; ++ni) {
      const int cIT = wc * 64 + ni * 16 + fr;
      f32x4 v = acc[mi][ni];
#pragma unroll
      for (int r = 0; r < 4; ++r)
        Gp[(size_t)(tc * 128 + rIT + r) * 512 + td * 128 + cIT] = v[r];
      if (tc != td)
        *(f32x4*)&Gp[(size_t)(td * 128 + cIT) * 512 + tc * 128 + rIT] = v;
    }
  }
}

// ---------------- K3: reduce split-K partials -> G bf16 --------------------
__global__ void greduce(const float* __restrict__ Gpart,
                        unsigned short* __restrict__ Gbf) {
  const int stride = gridDim.x * blockDim.x;
  const int n4 = 8 * 512 * 512 / 4;
  for (int i = blockIdx.x * blockDim.x + threadIdx.x; i < n4; i += stride) {
    float4v s = ((const float4v*)Gpart)[i];
#pragma unroll
    for (int c = 1; c < 4; ++c) {
      float4v t = ((const float4v*)(Gpart + (size_t)c * 8 * 512 * 512))[i];
      s.x += t.x; s.y += t.y; s.z += t.z; s.w += t.w;
    }
    u16x4 o;
    o.x = f2bf(s.x); o.y = f2bf(s.y); o.z = f2bf(s.z); o.w = f2bf(s.w);
    ((u16x4*)Gbf)[i] = o;
  }
}

// ---------------- K4: T_b = Wqk @ G_b (+ fused sumsq partials) -------------
__launch_bounds__(256)
__global__ void tall_gemm(const unsigned short* __restrict__ Wqk,
                          const unsigned short* __restrict__ Gbf,
                          unsigned short* __restrict__ Tbf,
                          float* __restrict__ ssPart) {
  __shared__ __align__(16) unsigned short lA[2][4096];
  __shared__ __align__(16) unsigned short lB[2][4096];
  __shared__ float ssL[128][2];
  const int tid = threadIdx.x, wave = tid >> 6, lane = tid & 63;
  const int wr = wave >> 1, wc = wave & 1, fr = lane & 15, kg = lane >> 4;
  const int rowBase = blockIdx.x * 128, colBase = blockIdx.y * 128;
  const int b = blockIdx.z;
  const unsigned short* Gb = Gbf + (size_t)b * 512 * 512;
  f32x4 acc[4][4] = {};
  const int sRow = wave * 16 + (lane >> 2);
  const int sK = (lane & 3) * 8;
  gemm_db<16>(Wqk + (size_t)(rowBase + sRow) * 512 + sK, 512,
              Gb + (size_t)(colBase + sRow) * 512 + sK, 512,
              lA, lB, wave, wr, wc, fr, kg, acc);
  unsigned short* Tb = Tbf + (size_t)b * 1024 * 512;
#pragma unroll
  for (int mi = 0; mi < 4; ++mi) {
    const int rbase = rowBase + wr * 64 + mi * 16 + kg * 4;
    f32x4 sacc = {0.f, 0.f, 0.f, 0.f};
#pragma unroll
    for (int ni = 0; ni < 4; ++ni) {
      const int col = colBase + wc * 64 + ni * 16 + fr;
      f32x4 v = acc[mi][ni];
#pragma unroll
      for (int r = 0; r < 4; ++r) {
        float w = bf2f((short)Wqk[(size_t)(rbase + r) * 512 + col]);
        Tb[(size_t)(rbase + r) * 512 + col] = f2bf(v[r]);
        sacc[r] += v[r] * w;
      }
    }
#pragma unroll
    for (int o = 1; o < 16; o <<= 1) {
#pragma unroll
      for (int r = 0; r < 4; ++r) sacc[r] += __shfl_xor(sacc[r], o);
    }
    if (fr == 0) {
#pragma unroll
      for (int r = 0; r < 4; ++r)
        ssL[wr * 64 + mi * 16 + kg * 4 + r][wc] = sacc[r];
    }
  }
  __syncthreads();
  if (tid < 128)
    ssPart[((size_t)blockIdx.y * 8 + b) * 1024 + rowBase + tid] =
        ssL[tid][0] + ssL[tid][1];
}

// ---------------- K5: fused S = T_q @ Wk^T -> normalize -> softmax ---------
__global__ void s_softmax(const unsigned short* __restrict__ Tbf,
                          const unsigned short* __restrict__ Wqk,
                          const float* __restrict__ ssPart,
                          const float* __restrict__ temp,
                          float* __restrict__ attnOut) {
  __shared__ float Sl[64 * 64];
  __shared__ float invq[64], invk[64];
  const int bh = blockIdx.x, b = bh >> 3, h = bh & 7;
  const unsigned short* qbase = Tbf + (size_t)(b * 1024 + h * 64) * 512;
  const unsigned short* kbase = Wqk + (size_t)(512 + h * 64) * 512;
  const int t = threadIdx.x;
  const int wave = t >> 6, lane = t & 63;
  const int wr = wave >> 1, wc = wave & 1, fr = lane & 15, kg = lane >> 4;
  f32x4 acc[2][2] = {};
  for (int kk = 0; kk < 512; kk += 32) {
    bf16x8 a[2], bb[2];
#pragma unroll
    for (int mi = 0; mi < 2; ++mi)
      a[mi] = *(const bf16x8*)(qbase + (size_t)(wr * 32 + mi * 16 + fr) * 512 + kk + kg * 8);
#pragma unroll
    for (int ni = 0; ni < 2; ++ni)
      bb[ni] = *(const bf16x8*)(kbase + (size_t)(wc * 32 + ni * 16 + fr) * 512 + kk + kg * 8);
#pragma unroll
    for (int mi = 0; mi < 2; ++mi)
#pragma unroll
      for (int ni = 0; ni < 2; ++ni)
        acc[mi][ni] = __builtin_amdgcn_mfma_f32_16x16x32_bf16(a[mi], bb[ni], acc[mi][ni], 0, 0, 0);
  }
#pragma unroll
  for (int mi = 0; mi < 2; ++mi)
#pragma unroll
    for (int ni = 0; ni < 2; ++ni) {
      f32x4 v = acc[mi][ni];
#pragma unroll
      for (int r = 0; r < 4; ++r)
        Sl[(wr * 32 + mi * 16 + kg * 4 + r) * 64 + wc * 32 + ni * 16 + fr] = v[r];
    }
  if (t < 128) {
    const int r = (t >> 6) * 512 + h * 64 + (t & 63);
    float s = 0.f;
#pragma unroll
    for (int nt = 0; nt < 4; ++nt) s += ssPart[((size_t)nt * 8 + b) * 1024 + r];
    float inv = 1.f / fmaxf(sqrtf(s), 1e-12f);
    if (t < 64) invq[t] = inv;
    else invk[t - 64] = inv;
  }
  __syncthreads();
  const float tmp = temp[h];
  const int c = t >> 2, q4 = t & 3;
  float lg[16];
  float mx = -1e30f;
#pragma unroll
  for (int j = 0; j < 16; ++j) {
    const int d = q4 * 16 + j;
    lg[j] = Sl[c * 64 + d] * invq[c] * invk[d] * tmp;
    mx = fmaxf(mx, lg[j]);
  }
  mx = fmaxf(mx, __shfl_xor(mx, 1));
  mx = fmaxf(mx, __shfl_xor(mx, 2));
  float sum = 0.f;
#pragma unroll
  for (int j = 0; j < 16; ++j) {
    lg[j] = __expf(lg[j] - mx);
    sum += lg[j];
  }
  sum += __shfl_xor(sum, 1);
  sum += __shfl_xor(sum, 2);
  const float inv = 1.f / sum;
#pragma unroll
  for (int j = 0; j < 16; ++j)
    attnOut[(size_t)bh * 4096 + c * 64 + q4 * 16 + j] = lg[j] * inv;
}

// ---------------- K6: Weff[b][:,h-block] = Wproj[:,h-block] @ attn ---------
__global__ void weff_kernel(const float* __restrict__ attn,
                            const float* __restrict__ Wproj,
                            unsigned short* __restrict__ Weff) {
  const int bh = blockIdx.x, eb = blockIdx.y;
  const int b = bh >> 3, h = bh & 7;
  __shared__ float at[64 * 64];
  for (int i = threadIdx.x; i < 4096; i += 256)
    at[i] = attn[(size_t)bh * 4096 + i];
  __syncthreads();
  const int e = eb * 64 + (threadIdx.x >> 2);
  const int dq = threadIdx.x & 3;
  float acc[16] = {};
  const float* wrow = Wproj + (size_t)e * 512 + h * 64;
  for (int c = 0; c < 64; ++c) {
    const float w = wrow[c];
#pragma unroll
    for (int j = 0; j < 16; ++j) acc[j] += w * at[c * 64 + dq * 16 + j];
  }
  unsigned short* outp = Weff + ((size_t)b * 512 + e) * 512 + h * 64 + dq * 16;
#pragma unroll
  for (int j = 0; j < 16; ++j) outp[j] = f2bf(acc[j]);
}

// ---------------- K7: Wcomb[b] = Weff[b] @ Wv  (= Weff · WvT^T) ------------
__launch_bounds__(256)
__global__ void wcomb_gemm(const unsigned short* __restrict__ WeffAll,
                           const unsigned short* __restrict__ WvT,
                           unsigned short* __restrict__ WcombAll) {
  __shared__ __align__(16) unsigned short lA[2][4096];
  __shared__ __align__(16) unsigned short lB[2][4096];
  const int tid = threadIdx.x, wave = tid >> 6, lane = tid & 63;
  const int wr = wave >> 1, wc = wave & 1, fr = lane & 15, kg = lane >> 4;
  const int b = blockIdx.z;
  const int rowBase = blockIdx.x * 128, colBase = blockIdx.y * 128;
  const unsigned short* A = WeffAll + (size_t)b * 512 * 512;
  f32x4 acc[4][4] = {};
  const int sRow = wave * 16 + (lane >> 2);
  const int sK = (lane & 3) * 8;
  gemm_db<16>(A + (size_t)(rowBase + sRow) * 512 + sK, 512,
              WvT + (size_t)(colBase + sRow) * 512 + sK, 512,
              lA, lB, wave, wr, wc, fr, kg, acc);
  unsigned short* Wc = WcombAll + (size_t)b * 512 * 512;
#pragma unroll
  for (int mi = 0; mi < 4; ++mi) {
    const int rbase = rowBase + wr * 64 + mi * 16 + kg * 4;
#pragma unroll
    for (int ni = 0; ni < 4; ++ni) {
      const int col = colBase + wc * 64 + ni * 16 + fr;
      f32x4 v = acc[mi][ni];
#pragma unroll
      for (int r = 0; r < 4; ++r)
        Wc[(size_t)(rbase + r) * 512 + col] = f2bf(v[r]);
    }
  }
}

// ---------------- K8: final = x @ Wcomb[b]^T + bproj -----------------------
__launch_bounds__(256)
__global__ void out_gemm(const unsigned short* __restrict__ Xbf,
                         const unsigned short* __restrict__ WcombAll,
                         const float* __restrict__ bias,
                         float* __restrict__ out) {
  __shared__ __align__(16) unsigned short lA[2][4096];
  __shared__ __align__(16) unsigned short lB[2][4096];
  const int tid = threadIdx.x, wave = tid >> 6, lane = tid & 63;
  const int wr = wave >> 1, wc = wave & 1, fr = lane & 15, kg = lane >> 4;
  const int b = blockIdx.z;
  const int rowBase = blockIdx.x * 128, colBase = blockIdx.y * 128;
  const unsigned short* A = Xbf + (size_t)b * 4096 * 512;
  const unsigned short* Bw = WcombAll + (size_t)b * 512 * 512;
  f32x4 acc[4][4] = {};
  const int sRow = wave * 16 + (lane >> 2);
  const int sK = (lane & 3) * 8;
  gemm_db<16>(A + (size_t)(rowBase + sRow) * 512 + sK, 512,
              Bw + (size_t)(colBase + sRow) * 512 + sK, 512,
              lA, lB, wave, wr, wc, fr, kg, acc);
#pragma unroll
  for (int mi = 0; mi < 4; ++mi) {
    const int rbase = rowBase + wr * 64 + mi * 16 + kg * 4;
#pragma unroll
    for (int ni = 0; ni < 4; ++ni) {
      const int col = colBase + wc * 64 + ni * 16 + fr;
      const float bcol = bias[col];
      f32x4 v = acc[mi][ni];
#pragma unroll
      for (int r = 0; r < 4; ++r)
        out[((size_t)b * 4096 + rbase + r) * 512 + col] = v[r] + bcol;
    }
  }
}

extern "C" void kernel_launch(void* const* d_in, const int* in_sizes, int n_in,
                              void* d_out, int out_size, void* d_ws, size_t ws_size,
                              hipStream_t stream) {
  const float* x = (const float*)d_in[0];      // [8][4096][512]
  const float* Wqkv = (const float*)d_in[1];   // [1536][512]
  const float* Wproj = (const float*)d_in[2];  // [512][512]
  const float* bproj = (const float*)d_in[3];  // [512]
  const float* temp = (const float*)d_in[4];   // [8]
  float* out = (float*)d_out;

  char* ws = (char*)d_ws;
  unsigned short* Xbf = (unsigned short*)(ws + 0);            // 33,554,432
  unsigned short* xT = (unsigned short*)(ws + 33554432);      // 33,554,432
  unsigned short* Wqk = (unsigned short*)(ws + 67108864);     //  1,048,576
  unsigned short* WvT = (unsigned short*)(ws + 68157440);     //    524,288
  float* Gpart = (float*)(ws + 68681728);                     // 33,554,432
  unsigned short* Gbf = (unsigned short*)(ws + 102236160);    //  4,194,304
  unsigned short* Tbf = (unsigned short*)(ws + 106430464);    //  8,388,608
  float* ssPart = (float*)(ws + 114819072);                   //    131,072
  float* attn = (float*)(ws + 114950144);                     //  1,048,576
  unsigned short* Weff = (unsigned short*)(ws + 115998720);   //  4,194,304
  unsigned short* Wcomb = (unsigned short*)(ws + 120193024);  //  4,194,304
  // total: 124,387,328 B

  cast_prep<<<dim3(64, 8, 9), 256, 0, stream>>>(x, Xbf, xT, Wqkv, Wqk, WvT);
  gsyrk<<<dim3(10, 4, 8), 256, 0, stream>>>(xT, Gpart);
  greduce<<<1024, 256, 0, stream>>>(Gpart, Gbf);
  tall_gemm<<<dim3(8, 4, 8), 256, 0, stream>>>(Wqk, Gbf, Tbf, ssPart);
  s_softmax<<<64, 256, 0, stream>>>(Tbf, Wqk, ssPart, temp, attn);
  weff_kernel<<<dim3(64, 8), 256, 0, stream>>>(attn, Wproj, Weff);
  wcomb_gemm<<<dim3(4, 4, 8), 256, 0, stream>>>(Weff, WvT, Wcomb);
  out_gemm<<<dim3(32, 4, 8), 256, 0, stream>>>(Xbf, Wcomb, bproj, out);
}